// Round 15
// baseline (465.788 us; speedup 1.0000x reference)
//
#include <hip/hip_runtime.h>

// out = tanh(((LN(z) @ W + b) * scale)/3)*3
// z (16384,1024) f32, W (1024,4096) f32, out (16384,4096) f32.
// Internal: zn and Wt in bf16 for MFMA (no fp32 MFMA on CDNA4).
// FINAL / BEST-MEASURED CONFIG (R1: 463.8 us, R14: 455.9 us; gemm 174-178 us, MfmaUtil 34.7%).
// Session evidence: 8 structural GEMM variants (schedules, swizzles, BK, occupancy, pipelining)
// all land 174-185 us spill-free; deeper register pipelines spill (R8/R13). Local minimum at
// HIP source level for this fused-epilogue accumulator footprint.
#define M_DIM 16384
#define K_DIM 1024
#define N_DIM 4096
#define T_TILES (K_DIM / 32)   // 32 K-tiles of BK=32

typedef __bf16 bf16x8 __attribute__((ext_vector_type(8)));
typedef float f32x16 __attribute__((ext_vector_type(16)));

__device__ __forceinline__ unsigned short f2bf(float f) {
    union { float f; unsigned int i; } v; v.f = f;
    unsigned int r = v.i + 0x7fffu + ((v.i >> 16) & 1u);  // round-to-nearest-even
    return (unsigned short)(r >> 16);
}
__device__ __forceinline__ unsigned int pack2(float lo, float hi) {
    return ((unsigned int)f2bf(lo)) | (((unsigned int)f2bf(hi)) << 16);
}

// ---------------- LayerNorm: one wave per row of 1024, fp32 in -> bf16 out ----------------
__global__ __launch_bounds__(256) void ln_kernel(
        const float* __restrict__ z,
        const float* __restrict__ gamma,
        const float* __restrict__ beta,
        unsigned short* __restrict__ zn) {
    const int wave = threadIdx.x >> 6;
    const int lane = threadIdx.x & 63;
    const size_t row = (size_t)blockIdx.x * 4 + wave;
    const float* zr = z + row * K_DIM;

    float4 x[4];
#pragma unroll
    for (int v = 0; v < 4; v++) x[v] = *(const float4*)(zr + v * 256 + lane * 4);

    float s = 0.f, ss = 0.f;
#pragma unroll
    for (int v = 0; v < 4; v++) {
        s  += x[v].x + x[v].y + x[v].z + x[v].w;
        ss += x[v].x * x[v].x + x[v].y * x[v].y + x[v].z * x[v].z + x[v].w * x[v].w;
    }
#pragma unroll
    for (int o = 32; o; o >>= 1) { s += __shfl_xor(s, o, 64); ss += __shfl_xor(ss, o, 64); }
    const float mean = s * (1.f / K_DIM);
    const float var = ss * (1.f / K_DIM) - mean * mean;
    const float rstd = rsqrtf(var + 1e-5f);

#pragma unroll
    for (int v = 0; v < 4; v++) {
        float4 g = *(const float4*)(gamma + v * 256 + lane * 4);
        float4 b = *(const float4*)(beta + v * 256 + lane * 4);
        float o0 = (x[v].x - mean) * rstd * g.x + b.x;
        float o1 = (x[v].y - mean) * rstd * g.y + b.y;
        float o2 = (x[v].z - mean) * rstd * g.z + b.z;
        float o3 = (x[v].w - mean) * rstd * g.w + b.w;
        uint2 q; q.x = pack2(o0, o1); q.y = pack2(o2, o3);
        *(uint2*)(zn + row * K_DIM + v * 256 + lane * 4) = q;
    }
}

// ---------------- Transpose+convert W fp32 (K,N) -> Wt bf16 (N,K) ----------------
__global__ __launch_bounds__(256) void tr_kernel(
        const float* __restrict__ W, unsigned short* __restrict__ Wt) {
    __shared__ float t[32][33];
    const int tx = threadIdx.x, ty = threadIdx.y;   // block (32, 8)
    const int n0 = blockIdx.x * 32, k0 = blockIdx.y * 32;
#pragma unroll
    for (int j = 0; j < 32; j += 8)
        t[ty + j][tx] = W[(size_t)(k0 + ty + j) * N_DIM + n0 + tx];
    __syncthreads();
#pragma unroll
    for (int j = 0; j < 32; j += 8)
        Wt[(size_t)(n0 + ty + j) * K_DIM + k0 + tx] = f2bf(t[tx][ty + j]);
}

// ---------------- GEMM: 256x256 tile, 8 waves, ring-4 LDS, counted-vmcnt pipeline ----------------
// zn (M,K)bf16 @ Wt (N,K)bf16 with 32x32x16 MFMA.
// LDS layout per 256x32 tile (A or B): 16B-unit index of (row, chunk c in [0,4)) is
//   u = row*4 + (c ^ ((row>>1)&3))
// global_load_lds writes lane l's 16B at base + l*16, so the staging source for unit u
// fetches row (u>>2), chunk ((u&3) ^ ((u>>3)&3)).
// Pipeline: ring of 4 K-tile slots, prefetch distance 3; per K-tile: one s_waitcnt vmcnt(8)
// + 2 phases, each {ds_read frags | issue one stage (2 x global_load_lds) | 8 MFMA} separated
// by raw s_barrier. vmcnt(8) keeps 2 tiles (8 loads) in flight; never drains to 0 mid-loop.
__device__ __forceinline__ void async_copy16(const unsigned short* g, unsigned short* l) {
    __builtin_amdgcn_global_load_lds(
        (const __attribute__((address_space(1))) unsigned int*)g,
        (__attribute__((address_space(3))) unsigned int*)l,
        16, 0, 0);
}

__global__ __launch_bounds__(512, 2) void gemm_kernel(
        const unsigned short* __restrict__ A,   // zn, (M, K) bf16
        const unsigned short* __restrict__ B,   // Wt, (N, K) bf16
        const float* __restrict__ bias,
        const float* __restrict__ scale,
        float* __restrict__ out) {
    __shared__ __align__(16) unsigned short As[4][256 * 32];   // 4 x 16 KB
    __shared__ __align__(16) unsigned short Bs[4][256 * 32];   // 4 x 16 KB  (total 128 KB)

    const int tid = threadIdx.x;
    const int wave = tid >> 6, lane = tid & 63;
    const int wm2 = wave >> 2, wn2 = wave & 3;   // 2x4 wave grid, each 128x64
    const int l31 = lane & 31, lhi = lane >> 5;

    // T1: XCD-aware block swizzle. nwg = 16*64 = 1024, divisible by 8.
    const int bid = blockIdx.y * gridDim.x + blockIdx.x;
    const int id2 = (bid & 7) * 128 + (bid >> 3);
    const int bm = id2 >> 4, bn = id2 & 15;      // bm in [0,64), bn in [0,16)

    // Staging source: thread tid covers unit u = q*512 + tid of each 256x32 tile.
    const int r0 = tid >> 2;
    const int c0 = ((tid & 3) ^ ((tid >> 3) & 3)) << 3;        // bf16 elem offset of swizzled chunk
    const unsigned short* ag0 = A + (size_t)(bm * 256 + r0) * K_DIM + c0;
    const unsigned short* bg0 = B + (size_t)(bn * 256 + r0) * K_DIM + c0;
    const int ldsu = wave * 512;   // elem offset of this wave's 64x16B chunk (q=0)

#define STAGE_A(t_, s_) do { \
        const unsigned short* g_ = ag0 + (t_) * 32; \
        async_copy16(g_,                 &As[s_][ldsu]); \
        async_copy16(g_ + 128 * K_DIM,   &As[s_][4096 + ldsu]); } while (0)
#define STAGE_B(t_, s_) do { \
        const unsigned short* g_ = bg0 + (t_) * 32; \
        async_copy16(g_,                 &Bs[s_][ldsu]); \
        async_copy16(g_ + 128 * K_DIM,   &Bs[s_][4096 + ldsu]); } while (0)

    f32x16 acc[4][2] = {};
    const int swz = (l31 >> 1) & 3;   // row-dependent XOR for fragment reads

    // Prologue: prefetch K-tiles 0,1,2 (12 loads in flight; issue order = tile order).
    STAGE_A(0, 0); STAGE_B(0, 0);
    STAGE_A(1, 1); STAGE_B(1, 1);
    STAGE_A(2, 2); STAGE_B(2, 2);

#pragma unroll 4
    for (int t = 0; t < T_TILES; ++t) {
        const int s = t & 3;
        const int ts = t + 3, ss = ts & 3;

        // Counted wait: retire tile t's 4 loads; keep tiles t+1,t+2 (8 loads) in flight.
        if (t <= T_TILES - 3)      asm volatile("s_waitcnt vmcnt(8)" ::: "memory");
        else if (t == T_TILES - 2) asm volatile("s_waitcnt vmcnt(4)" ::: "memory");
        else                       asm volatile("s_waitcnt vmcnt(0)" ::: "memory");
        __builtin_amdgcn_s_barrier();
        asm volatile("" ::: "memory");

        const unsigned short* as_ = As[s];
        const unsigned short* bs_ = Bs[s];
        bf16x8 a[2][2], b[2][2];

        // ---- phase A: rows [0,64) of the wave tile, all 64 cols, full BK=32 ----
#pragma unroll
        for (int i = 0; i < 2; ++i)
#pragma unroll
            for (int ks = 0; ks < 2; ++ks)
                a[i][ks] = *(const bf16x8*)&as_[(wm2 * 128 + i * 32 + l31) * 32 + (((2 * ks + lhi) ^ swz) << 3)];
#pragma unroll
        for (int j = 0; j < 2; ++j)
#pragma unroll
            for (int ks = 0; ks < 2; ++ks)
                b[j][ks] = *(const bf16x8*)&bs_[(wn2 * 64 + j * 32 + l31) * 32 + (((2 * ks + lhi) ^ swz) << 3)];
        if (ts < T_TILES) STAGE_A(ts, ss);   // writes slot (t-1)&3: no reader during tiles t..t+2
        __builtin_amdgcn_s_setprio(1);
#pragma unroll
        for (int i = 0; i < 2; ++i)
#pragma unroll
            for (int j = 0; j < 2; ++j)
#pragma unroll
                for (int ks = 0; ks < 2; ++ks)
                    acc[i][j] = __builtin_amdgcn_mfma_f32_32x32x16_bf16(a[i][ks], b[j][ks], acc[i][j], 0, 0, 0);
        __builtin_amdgcn_s_setprio(0);
        asm volatile("" ::: "memory");
        __builtin_amdgcn_s_barrier();
        asm volatile("" ::: "memory");

        // ---- phase B: rows [64,128) of the wave tile (B frags reused from registers) ----
#pragma unroll
        for (int i = 0; i < 2; ++i)
#pragma unroll
            for (int ks = 0; ks < 2; ++ks)
                a[i][ks] = *(const bf16x8*)&as_[(wm2 * 128 + 64 + i * 32 + l31) * 32 + (((2 * ks + lhi) ^ swz) << 3)];
        if (ts < T_TILES) STAGE_B(ts, ss);
        __builtin_amdgcn_s_setprio(1);
#pragma unroll
        for (int i = 0; i < 2; ++i)
#pragma unroll
            for (int j = 0; j < 2; ++j)
#pragma unroll
                for (int ks = 0; ks < 2; ++ks)
                    acc[2 + i][j] = __builtin_amdgcn_mfma_f32_32x32x16_bf16(a[i][ks], b[j][ks], acc[2 + i][j], 0, 0, 0);
        __builtin_amdgcn_s_setprio(0);
        asm volatile("" ::: "memory");
    }
#undef STAGE_A
#undef STAGE_B

    // Epilogue: out = 3*tanh(x/3) = 3 - 6/(exp2(x*2/(3 ln2)) + 1); saturates correctly at +-inf.
    const float mfac = scale[0] * 0.96179669392236f;   // scale * 2/(3*ln2)
#pragma unroll
    for (int j = 0; j < 2; ++j) {
        const int gcol = bn * 256 + wn2 * 64 + j * 32 + l31;
        const float bv = bias[gcol];
#pragma unroll
        for (int i = 0; i < 4; ++i) {
            const int rbase = bm * 256 + wm2 * 128 + i * 32 + 4 * lhi;
#pragma unroll
            for (int r = 0; r < 16; ++r) {
                const int grow = rbase + (r & 3) + 8 * (r >> 2);
                float tv = (acc[i][j][r] + bv) * mfac;
                float e = __builtin_amdgcn_exp2f(tv);
                out[(size_t)grow * N_DIM + gcol] = 3.f - 6.f * __builtin_amdgcn_rcpf(e + 1.f);
            }
        }
    }
}

extern "C" void kernel_launch(void* const* d_in, const int* in_sizes, int n_in,
                              void* d_out, int out_size, void* d_ws, size_t ws_size,
                              hipStream_t stream) {
    const float* z     = (const float*)d_in[0];
    const float* gamma = (const float*)d_in[1];
    const float* beta  = (const float*)d_in[2];
    const float* W     = (const float*)d_in[3];
    const float* b     = (const float*)d_in[4];
    const float* scale = (const float*)d_in[5];
    float* out = (float*)d_out;

    unsigned short* zn = (unsigned short*)d_ws;                 // 16384*1024 bf16 = 32 MB
    unsigned short* Wt = zn + (size_t)M_DIM * K_DIM;            // 4096*1024 bf16  =  8 MB

    ln_kernel<<<M_DIM / 4, 256, 0, stream>>>(z, gamma, beta, zn);
    tr_kernel<<<dim3(N_DIM / 32, K_DIM / 32), dim3(32, 8), 0, stream>>>(W, Wt);
    gemm_kernel<<<dim3(N_DIM / 256, M_DIM / 256), 512, 0, stream>>>(zn, Wt, b, scale, out);
}

// Round 18
// 451.300 us; speedup vs baseline: 1.0321x; 1.0321x over previous
//
#include <hip/hip_runtime.h>

// out = tanh(((LN(z) @ W + b) * scale)/3)*3
// z (16384,1024) f32, W (1024,4096) f32, out (16384,4096) f32.
// Internal: zn and Wt in bf16 for MFMA (no fp32 MFMA on CDNA4).
// BEST-MEASURED CONFIG (R1 463.8 / R14 455.9 / R15 465.8 us; gemm 174-179 us, MfmaUtil 34.4%).
// Single change under test: REMOVED s_setprio around MFMA clusters — T5 is documented
// null-to-negative on lockstep 2-phase GEMM structures (m190: -14 TF @8k within-probe A/B).
// Everything else byte-identical to the verified R14 kernel.
#define M_DIM 16384
#define K_DIM 1024
#define N_DIM 4096
#define T_TILES (K_DIM / 32)   // 32 K-tiles of BK=32

typedef __bf16 bf16x8 __attribute__((ext_vector_type(8)));
typedef float f32x16 __attribute__((ext_vector_type(16)));

__device__ __forceinline__ unsigned short f2bf(float f) {
    union { float f; unsigned int i; } v; v.f = f;
    unsigned int r = v.i + 0x7fffu + ((v.i >> 16) & 1u);  // round-to-nearest-even
    return (unsigned short)(r >> 16);
}
__device__ __forceinline__ unsigned int pack2(float lo, float hi) {
    return ((unsigned int)f2bf(lo)) | (((unsigned int)f2bf(hi)) << 16);
}

// ---------------- LayerNorm: one wave per row of 1024, fp32 in -> bf16 out ----------------
__global__ __launch_bounds__(256) void ln_kernel(
        const float* __restrict__ z,
        const float* __restrict__ gamma,
        const float* __restrict__ beta,
        unsigned short* __restrict__ zn) {
    const int wave = threadIdx.x >> 6;
    const int lane = threadIdx.x & 63;
    const size_t row = (size_t)blockIdx.x * 4 + wave;
    const float* zr = z + row * K_DIM;

    float4 x[4];
#pragma unroll
    for (int v = 0; v < 4; v++) x[v] = *(const float4*)(zr + v * 256 + lane * 4);

    float s = 0.f, ss = 0.f;
#pragma unroll
    for (int v = 0; v < 4; v++) {
        s  += x[v].x + x[v].y + x[v].z + x[v].w;
        ss += x[v].x * x[v].x + x[v].y * x[v].y + x[v].z * x[v].z + x[v].w * x[v].w;
    }
#pragma unroll
    for (int o = 32; o; o >>= 1) { s += __shfl_xor(s, o, 64); ss += __shfl_xor(ss, o, 64); }
    const float mean = s * (1.f / K_DIM);
    const float var = ss * (1.f / K_DIM) - mean * mean;
    const float rstd = rsqrtf(var + 1e-5f);

#pragma unroll
    for (int v = 0; v < 4; v++) {
        float4 g = *(const float4*)(gamma + v * 256 + lane * 4);
        float4 b = *(const float4*)(beta + v * 256 + lane * 4);
        float o0 = (x[v].x - mean) * rstd * g.x + b.x;
        float o1 = (x[v].y - mean) * rstd * g.y + b.y;
        float o2 = (x[v].z - mean) * rstd * g.z + b.z;
        float o3 = (x[v].w - mean) * rstd * g.w + b.w;
        uint2 q; q.x = pack2(o0, o1); q.y = pack2(o2, o3);
        *(uint2*)(zn + row * K_DIM + v * 256 + lane * 4) = q;
    }
}

// ---------------- Transpose+convert W fp32 (K,N) -> Wt bf16 (N,K) ----------------
__global__ __launch_bounds__(256) void tr_kernel(
        const float* __restrict__ W, unsigned short* __restrict__ Wt) {
    __shared__ float t[32][33];
    const int tx = threadIdx.x, ty = threadIdx.y;   // block (32, 8)
    const int n0 = blockIdx.x * 32, k0 = blockIdx.y * 32;
#pragma unroll
    for (int j = 0; j < 32; j += 8)
        t[ty + j][tx] = W[(size_t)(k0 + ty + j) * N_DIM + n0 + tx];
    __syncthreads();
#pragma unroll
    for (int j = 0; j < 32; j += 8)
        Wt[(size_t)(n0 + ty + j) * K_DIM + k0 + tx] = f2bf(t[tx][ty + j]);
}

// ---------------- GEMM: 256x256 tile, 8 waves, ring-4 LDS, counted-vmcnt pipeline ----------------
// zn (M,K)bf16 @ Wt (N,K)bf16 with 32x32x16 MFMA.
// LDS layout per 256x32 tile (A or B): 16B-unit index of (row, chunk c in [0,4)) is
//   u = row*4 + (c ^ ((row>>1)&3))
// global_load_lds writes lane l's 16B at base + l*16, so the staging source for unit u
// fetches row (u>>2), chunk ((u&3) ^ ((u>>3)&3)).
// Pipeline: ring of 4 K-tile slots, prefetch distance 3; per K-tile: one s_waitcnt vmcnt(8)
// + 2 phases, each {ds_read frags | issue one stage (2 x global_load_lds) | 8 MFMA} separated
// by raw s_barrier. vmcnt(8) keeps 2 tiles (8 loads) in flight; never drains to 0 mid-loop.
__device__ __forceinline__ void async_copy16(const unsigned short* g, unsigned short* l) {
    __builtin_amdgcn_global_load_lds(
        (const __attribute__((address_space(1))) unsigned int*)g,
        (__attribute__((address_space(3))) unsigned int*)l,
        16, 0, 0);
}

__global__ __launch_bounds__(512, 2) void gemm_kernel(
        const unsigned short* __restrict__ A,   // zn, (M, K) bf16
        const unsigned short* __restrict__ B,   // Wt, (N, K) bf16
        const float* __restrict__ bias,
        const float* __restrict__ scale,
        float* __restrict__ out) {
    __shared__ __align__(16) unsigned short As[4][256 * 32];   // 4 x 16 KB
    __shared__ __align__(16) unsigned short Bs[4][256 * 32];   // 4 x 16 KB  (total 128 KB)

    const int tid = threadIdx.x;
    const int wave = tid >> 6, lane = tid & 63;
    const int wm2 = wave >> 2, wn2 = wave & 3;   // 2x4 wave grid, each 128x64
    const int l31 = lane & 31, lhi = lane >> 5;

    // T1: XCD-aware block swizzle. nwg = 16*64 = 1024, divisible by 8.
    const int bid = blockIdx.y * gridDim.x + blockIdx.x;
    const int id2 = (bid & 7) * 128 + (bid >> 3);
    const int bm = id2 >> 4, bn = id2 & 15;      // bm in [0,64), bn in [0,16)

    // Staging source: thread tid covers unit u = q*512 + tid of each 256x32 tile.
    const int r0 = tid >> 2;
    const int c0 = ((tid & 3) ^ ((tid >> 3) & 3)) << 3;        // bf16 elem offset of swizzled chunk
    const unsigned short* ag0 = A + (size_t)(bm * 256 + r0) * K_DIM + c0;
    const unsigned short* bg0 = B + (size_t)(bn * 256 + r0) * K_DIM + c0;
    const int ldsu = wave * 512;   // elem offset of this wave's 64x16B chunk (q=0)

#define STAGE_A(t_, s_) do { \
        const unsigned short* g_ = ag0 + (t_) * 32; \
        async_copy16(g_,                 &As[s_][ldsu]); \
        async_copy16(g_ + 128 * K_DIM,   &As[s_][4096 + ldsu]); } while (0)
#define STAGE_B(t_, s_) do { \
        const unsigned short* g_ = bg0 + (t_) * 32; \
        async_copy16(g_,                 &Bs[s_][ldsu]); \
        async_copy16(g_ + 128 * K_DIM,   &Bs[s_][4096 + ldsu]); } while (0)

    f32x16 acc[4][2] = {};
    const int swz = (l31 >> 1) & 3;   // row-dependent XOR for fragment reads

    // Prologue: prefetch K-tiles 0,1,2 (12 loads in flight; issue order = tile order).
    STAGE_A(0, 0); STAGE_B(0, 0);
    STAGE_A(1, 1); STAGE_B(1, 1);
    STAGE_A(2, 2); STAGE_B(2, 2);

#pragma unroll 4
    for (int t = 0; t < T_TILES; ++t) {
        const int s = t & 3;
        const int ts = t + 3, ss = ts & 3;

        // Counted wait: retire tile t's 4 loads; keep tiles t+1,t+2 (8 loads) in flight.
        if (t <= T_TILES - 3)      asm volatile("s_waitcnt vmcnt(8)" ::: "memory");
        else if (t == T_TILES - 2) asm volatile("s_waitcnt vmcnt(4)" ::: "memory");
        else                       asm volatile("s_waitcnt vmcnt(0)" ::: "memory");
        __builtin_amdgcn_s_barrier();
        asm volatile("" ::: "memory");

        const unsigned short* as_ = As[s];
        const unsigned short* bs_ = Bs[s];
        bf16x8 a[2][2], b[2][2];

        // ---- phase A: rows [0,64) of the wave tile, all 64 cols, full BK=32 ----
#pragma unroll
        for (int i = 0; i < 2; ++i)
#pragma unroll
            for (int ks = 0; ks < 2; ++ks)
                a[i][ks] = *(const bf16x8*)&as_[(wm2 * 128 + i * 32 + l31) * 32 + (((2 * ks + lhi) ^ swz) << 3)];
#pragma unroll
        for (int j = 0; j < 2; ++j)
#pragma unroll
            for (int ks = 0; ks < 2; ++ks)
                b[j][ks] = *(const bf16x8*)&bs_[(wn2 * 64 + j * 32 + l31) * 32 + (((2 * ks + lhi) ^ swz) << 3)];
        if (ts < T_TILES) STAGE_A(ts, ss);   // writes slot (t-1)&3: no reader during tiles t..t+2
#pragma unroll
        for (int i = 0; i < 2; ++i)
#pragma unroll
            for (int j = 0; j < 2; ++j)
#pragma unroll
                for (int ks = 0; ks < 2; ++ks)
                    acc[i][j] = __builtin_amdgcn_mfma_f32_32x32x16_bf16(a[i][ks], b[j][ks], acc[i][j], 0, 0, 0);
        asm volatile("" ::: "memory");
        __builtin_amdgcn_s_barrier();
        asm volatile("" ::: "memory");

        // ---- phase B: rows [64,128) of the wave tile (B frags reused from registers) ----
#pragma unroll
        for (int i = 0; i < 2; ++i)
#pragma unroll
            for (int ks = 0; ks < 2; ++ks)
                a[i][ks] = *(const bf16x8*)&as_[(wm2 * 128 + 64 + i * 32 + l31) * 32 + (((2 * ks + lhi) ^ swz) << 3)];
        if (ts < T_TILES) STAGE_B(ts, ss);
#pragma unroll
        for (int i = 0; i < 2; ++i)
#pragma unroll
            for (int j = 0; j < 2; ++j)
#pragma unroll
                for (int ks = 0; ks < 2; ++ks)
                    acc[2 + i][j] = __builtin_amdgcn_mfma_f32_32x32x16_bf16(a[i][ks], b[j][ks], acc[2 + i][j], 0, 0, 0);
        asm volatile("" ::: "memory");
    }
#undef STAGE_A
#undef STAGE_B

    // Epilogue: out = 3*tanh(x/3) = 3 - 6/(exp2(x*2/(3 ln2)) + 1); saturates correctly at +-inf.
    const float mfac = scale[0] * 0.96179669392236f;   // scale * 2/(3*ln2)
#pragma unroll
    for (int j = 0; j < 2; ++j) {
        const int gcol = bn * 256 + wn2 * 64 + j * 32 + l31;
        const float bv = bias[gcol];
#pragma unroll
        for (int i = 0; i < 4; ++i) {
            const int rbase = bm * 256 + wm2 * 128 + i * 32 + 4 * lhi;
#pragma unroll
            for (int r = 0; r < 16; ++r) {
                const int grow = rbase + (r & 3) + 8 * (r >> 2);
                float tv = (acc[i][j][r] + bv) * mfac;
                float e = __builtin_amdgcn_exp2f(tv);
                out[(size_t)grow * N_DIM + gcol] = 3.f - 6.f * __builtin_amdgcn_rcpf(e + 1.f);
            }
        }
    }
}

extern "C" void kernel_launch(void* const* d_in, const int* in_sizes, int n_in,
                              void* d_out, int out_size, void* d_ws, size_t ws_size,
                              hipStream_t stream) {
    const float* z     = (const float*)d_in[0];
    const float* gamma = (const float*)d_in[1];
    const float* beta  = (const float*)d_in[2];
    const float* W     = (const float*)d_in[3];
    const float* b     = (const float*)d_in[4];
    const float* scale = (const float*)d_in[5];
    float* out = (float*)d_out;

    unsigned short* zn = (unsigned short*)d_ws;                 // 16384*1024 bf16 = 32 MB
    unsigned short* Wt = zn + (size_t)M_DIM * K_DIM;            // 4096*1024 bf16  =  8 MB

    ln_kernel<<<M_DIM / 4, 256, 0, stream>>>(z, gamma, beta, zn);
    tr_kernel<<<dim3(N_DIM / 32, K_DIM / 32), dim3(32, 8), 0, stream>>>(W, Wt);
    gemm_kernel<<<dim3(N_DIM / 256, M_DIM / 256), 512, 0, stream>>>(zn, Wt, b, scale, out);
}